// Round 8
// baseline (5039.030 us; speedup 1.0000x reference)
//
#include <hip/hip_runtime.h>
#include <stdint.h>

// AR(12) rollout: 12 sequential GEMMs of [B=128 x K=24576] x [K x N=2048].
// R7: per-step kernel with FUSED reduction (last-block-per-slice via device
// atomic counter -> no reduce dispatches, no spin/deadlock risk), both A and
// B staged via global_load_lds at BK=32 (32KB LDS, 3 blocks/CU), fp16
// single-product with exact power-of-2 per-slot scaling (R4/R5 numerics).

typedef _Float16 f16x8 __attribute__((ext_vector_type(8)));
typedef float    f32x4 __attribute__((ext_vector_type(4)));

#define B_ 128
#define N_ 2048
#define P_ 12
#define K_ (P_*N_)          // 24576
#define KSPLIT 48
#define KCH (K_/KSPLIT)     // 512 (slot-aligned: 4 chunks per 2048-slot)
#define NPH (KCH/32)        // 16 phases of BK=32
#define NT 16               // N-tiles of 128
#define NKP (K_/64)         // 384 BK64 W-tiles per nt column

#define WPK_BYTES    ((size_t)NT*NKP*16384)     // 100,663,296 (fp16, tiled)
#define H_SLOT_BYTES ((size_t)B_*N_*2)          // 524,288 per window slot
#define H_BYTES      (23*H_SLOT_BYTES)          // 12,058,624
#define PART_BYTES   ((size_t)KSPLIT*B_*N_*4)   // 50,331,648
#define CNT_INTS     (12*16*4)
#define WS_NEEDED    (WPK_BYTES + H_BYTES + PART_BYTES + CNT_INTS*4)

// Scale exponents for y_{t+1} (t=0..10): e = round(7.29 + 5.50*t) from the
// variance recursion sigma(y_1)=sqrt(24576), growth sqrt(2048) per step.
__device__ __constant__ int E_TAB[11] = {7, 13, 18, 24, 29, 35, 40, 46, 51, 57, 62};

__device__ __forceinline__ int e_of_slot(int g) {   // g = global slot 0..22
    return (g < 12) ? 0 : E_TAB[g - 12];
}
__device__ __forceinline__ float pow2f(int e) {      // exact 2^e, |e| < 127
    return __uint_as_float((uint32_t)(127 + e) << 23);
}

union F16x8 { _Float16 h[8]; uint4 q; };

// H (window) layout: [slot][kblk=k/32][b][k%32] fp16, XOR swizzle per 8KB tile:
// byte = (b*64 + (k&31)*2) ^ ((b&7)<<4). Linear global_load_lds staging +
// conflict-free ds_read_b128 fragments (R1-R5 proven).
__device__ __forceinline__ uint32_t h_off(int slot, int b, int k) {
    uint32_t t = (uint32_t)((b << 6) + ((k & 31) << 1)) ^ (uint32_t)((b & 7) << 4);
    return (uint32_t)slot * (uint32_t)H_SLOT_BYTES + (uint32_t)(k >> 5) * 8192u + t;
}
// Wp (B) layout: tile(nt, pk) = 16 KB covering BK=64 x BN=128, two 8KB halves:
// byte(ksub,c,ko) = ksub*8192 + ((c*64 + ko*16) ^ ((c&7)<<4)), c = n % 128.
__device__ __forceinline__ size_t w_tile_base(int nt, int pk) {
    return ((size_t)nt * NKP + (size_t)pk) * 16384;
}

// ---------------- prep: x->H (blocks 0..127), W->Wp (128..6271), cnt=0 (6272) ----------------
__global__ void prep_all(const float* __restrict__ x, const float* __restrict__ W,
                         char* __restrict__ Wp, char* __restrict__ H, int* __restrict__ cnt)
{
    __shared__ float tile[128][68];   // +4 pad
    int bid = blockIdx.x, t = threadIdx.x;
    if (bid == 6272) {
        for (int i = t; i < CNT_INTS; i += 256) cnt[i] = 0;
        return;
    }
    if (bid < 128) {
        int tg = bid * 256 + t;                 // 32768 threads: (b, n-octet)
        int b = tg >> 8;
        int n0 = (tg & 255) << 3;
        const float4* s4 = (const float4*)(x + ((size_t)b * N_ + n0) * P_);
        float4 tmp[24];
        #pragma unroll
        for (int i2 = 0; i2 < 24; ++i2) tmp[i2] = s4[i2];
        #pragma unroll
        for (int p = 0; p < 12; ++p) {
            F16x8 o;
            #pragma unroll
            for (int q = 0; q < 8; ++q) {
                int fi = q * 12 + p;            // compile-time constant
                float4 blk = tmp[fi >> 2];
                float f = ((fi & 3) == 0) ? blk.x : ((fi & 3) == 1) ? blk.y : ((fi & 3) == 2) ? blk.z : blk.w;
                o.h[q] = (_Float16)f;
            }
            *(uint4*)(H + h_off(p, b, n0)) = o.q;
        }
        return;
    }
    int u = bid - 128;                          // 0..6143 = 16 nt x 384 pk
    int nt = u / NKP, pk = u % NKP;
    int i  = pk >> 5;                           // W slice 0..11
    int k0 = (pk & 31) << 6;                    // k-in-slice
    int j0 = nt << 7;
    #pragma unroll
    for (int pass = 0; pass < 8; ++pass) {      // coalesced fp32 reads along k
        int jl = pass * 16 + (t >> 4);
        int kq = (t & 15) * 4;
        float4 v = *(const float4*)(W + ((size_t)i * N_ + (j0 + jl)) * N_ + k0 + kq);
        tile[jl][kq + 0] = v.x; tile[jl][kq + 1] = v.y;
        tile[jl][kq + 2] = v.z; tile[jl][kq + 3] = v.w;
    }
    __syncthreads();
    int ksub = t >> 7, c = t & 127;
    char* base = Wp + w_tile_base(nt, pk) + (ksub << 13);
    #pragma unroll
    for (int ko = 0; ko < 4; ++ko) {
        F16x8 o;
        #pragma unroll
        for (int q = 0; q < 8; ++q) o.h[q] = (_Float16)tile[c][ksub * 32 + ko * 8 + q];
        uint32_t off = (uint32_t)((c << 6) + (ko << 4)) ^ (uint32_t)((c & 7) << 4);
        *(uint4*)(base + off) = o.q;
    }
}

// ---------------- per-step GEMM + fused reduce ----------------
// grid 768 = 16 nt x 48 ks (bid%8 == ks%8 -> A-chunk sharers on one XCD).
// 4 waves as 2x2; wave tile 64x64; block tile 128x128; BK=32 double-buffered.
__global__ __launch_bounds__(256, 3) void gemm_fused(
        const char* __restrict__ Wp, char* __restrict__ H,
        float* __restrict__ partial, int* __restrict__ cnt,
        float* __restrict__ out, int t)
{
    __shared__ alignas(16) char ldsA[2][8192];
    __shared__ alignas(16) char ldsB[2][8192];
    __shared__ int lastmask;
    const int tid  = threadIdx.x;
    const int lane = tid & 63;
    const int wv   = tid >> 6;
    const int wr   = wv >> 1;                   // M half
    const int wc   = wv & 1;                    // N half
    const int bid  = blockIdx.x;
    const int ks   = bid % KSPLIT;
    const int nt   = bid / KSPLIT;
    const int l15  = lane & 15;
    const int ko   = lane >> 4;                 // k-octet 0..3
    const int kbase = ks * KCH;

    uint32_t aoff[4], boff[4];
    #pragma unroll
    for (int m = 0; m < 4; ++m) {
        int row = (wr << 6) + (m << 4) + l15;
        aoff[m] = (uint32_t)((row << 6) + (ko << 4)) ^ (uint32_t)((row & 7) << 4);
    }
    #pragma unroll
    for (int n = 0; n < 4; ++n) {
        int c = (wc << 6) + (n << 4) + l15;
        boff[n] = (uint32_t)((c << 6) + (ko << 4)) ^ (uint32_t)((c & 7) << 4);
    }

    auto stage = [&](int buf, int ph) {         // A 8KB + B 8KB, linear
        int kg = kbase + (ph << 5);
        const char* sA = H + (size_t)(t + (kg >> 11)) * H_SLOT_BYTES
                       + (uint32_t)(((kg & 2047) >> 5) << 13);
        const char* sB = Wp + w_tile_base(nt, (ks << 3) + (ph >> 1)) + (uint32_t)((ph & 1) << 13);
        #pragma unroll
        for (int j = 0; j < 2; ++j) {
            uint32_t o = (uint32_t)(j << 12) + (uint32_t)(tid << 4);
            __builtin_amdgcn_global_load_lds(
                (const __attribute__((address_space(1))) void*)(sA + o),
                (__attribute__((address_space(3))) void*)&ldsA[buf][(j << 12) + (wv << 10)], 16, 0, 0);
            __builtin_amdgcn_global_load_lds(
                (const __attribute__((address_space(1))) void*)(sB + o),
                (__attribute__((address_space(3))) void*)&ldsB[buf][(j << 12) + (wv << 10)], 16, 0, 0);
        }
    };

    f32x4 acc[4][4];
    #pragma unroll
    for (int m = 0; m < 4; ++m)
        #pragma unroll
        for (int n = 0; n < 4; ++n) acc[m][n] = (f32x4){0.f, 0.f, 0.f, 0.f};

    stage(0, 0);
    __syncthreads();                            // compiler drains vmcnt before barrier

    for (int ph = 0; ph < NPH; ++ph) {
        if (ph + 1 < NPH) stage((ph + 1) & 1, ph + 1);   // prefetch other buffer
        const char* lA = &ldsA[ph & 1][0];
        const char* lB = &ldsB[ph & 1][0];
        f16x8 ah[4], bf[4];
        #pragma unroll
        for (int m = 0; m < 4; ++m) ah[m] = *(const f16x8*)(lA + aoff[m]);
        #pragma unroll
        for (int n = 0; n < 4; ++n) bf[n] = *(const f16x8*)(lB + boff[n]);
        #pragma unroll
        for (int m = 0; m < 4; ++m)
            #pragma unroll
            for (int n = 0; n < 4; ++n)
                acc[m][n] = __builtin_amdgcn_mfma_f32_16x16x32_f16(ah[m], bf[n], acc[m][n], 0, 0, 0);
        __syncthreads();                        // reads done before next stage overwrites
    }

    // C/D layout (verified R0-R5): col = lane&15, row = (lane>>4)*4 + reg
    const int r0 = (lane >> 4) << 2;
    float* pb = partial + ((size_t)ks * B_ + (wr << 6) + r0) * N_ + (nt << 7) + (wc << 6) + l15;
    #pragma unroll
    for (int m = 0; m < 4; ++m)
        #pragma unroll
        for (int n = 0; n < 4; ++n)
            #pragma unroll
            for (int r = 0; r < 4; ++r)
                pb[(size_t)(m * 16 + r) * N_ + n * 16] = acc[m][n][r];

    // ---- fused reduce: last block per (nt, b-quarter) slice does the sum ----
    __threadfence();                            // flush partial to device scope
    if (tid == 0) lastmask = 0;
    __syncthreads();                            // all stores fenced before any RMW
    if (tid < 4) {
        int old = atomicAdd(&cnt[((t * NT + nt) << 2) + tid], 1);
        if (old == KSPLIT - 1) atomicOr(&lastmask, 1 << tid);
    }
    __syncthreads();
    int mask = lastmask;
    if (mask == 0) return;

    float sc[12];
    #pragma unroll
    for (int i = 0; i < 12; ++i) sc[i] = pow2f(e_of_slot(t + i));
    float ds = (t < 11) ? pow2f(-E_TAB[t]) : 0.f;

    for (int bq = 0; bq < 4; ++bq) {
        if (!((mask >> bq) & 1)) continue;
        for (int pass = 0; pass < 16; ++pass) {
            int e = pass * 256 + tid;           // 4096 elems: 32 b x 128 n
            int b = (bq << 5) + (e >> 7);
            int n = (nt << 7) + (e & 127);
            float s = 0.f;
            #pragma unroll 4
            for (int k2 = 0; k2 < KSPLIT; ++k2)
                s += partial[((size_t)k2 * B_ + b) * N_ + n] * sc[k2 >> 2];
            out[((size_t)b * N_ + n) * P_ + t] = s;
            if (t < 11)
                *(_Float16*)(H + h_off(12 + t, b, n)) = (_Float16)(s * ds);
        }
    }
}

// ---------------- insurance: naive fp32 path if workspace is too small ----------------
__global__ void naive_step(const float* __restrict__ x, const float* __restrict__ W,
                           float* __restrict__ out, int t)
{
    int tid = blockIdx.x * 256 + threadIdx.x;   // 262144 threads: (b, j)
    int b = tid >> 11;
    int j = tid & (N_ - 1);
    float acc = 0.f;
    for (int i = 0; i < 12; ++i) {
        int g = t + i;
        const float* src = (g < 12) ? (x   + (size_t)b * (N_ * 12) + g)
                                    : (out + (size_t)b * (N_ * 12) + (g - 12));
        const float* wr = W + ((size_t)i * N_ + j) * N_;
        for (int k = 0; k < N_; ++k)
            acc += wr[k] * src[(size_t)k * 12];
    }
    out[((size_t)b * N_ + j) * 12 + t] = acc;
}

extern "C" void kernel_launch(void* const* d_in, const int* in_sizes, int n_in,
                              void* d_out, int out_size, void* d_ws, size_t ws_size,
                              hipStream_t stream)
{
    const float* x = (const float*)d_in[0];
    const float* W = (const float*)d_in[1];
    float* out = (float*)d_out;

    if (ws_size < WS_NEEDED) {                  // fallback: correct but slow
        for (int t = 0; t < 12; ++t)
            naive_step<<<1024, 256, 0, stream>>>(x, W, out, t);
        return;
    }

    char* Wp = (char*)d_ws;
    char* H  = Wp + WPK_BYTES;
    float* partial = (float*)(H + H_BYTES);
    int* cnt = (int*)(partial + (PART_BYTES / 4));

    prep_all<<<6273, 256, 0, stream>>>(x, W, Wp, H, cnt);
    for (int t = 0; t < 12; ++t)
        gemm_fused<<<768, 256, 0, stream>>>(Wp, H, partial, cnt, out, t);
}

// Round 9
// 451.686 us; speedup vs baseline: 11.1560x; 11.1560x over previous
//
#include <hip/hip_runtime.h>
#include <stdint.h>

// AR(12) rollout: 12 sequential GEMMs of [B=128 x K=24576] x [K x N=2048].
// R8 = R5 skeleton + the partial-round-trip fix discovered via R7's counters:
// partials were 50MB fp32 -> evicted to HBM (6.2MB/XCD > 4MB L2) -> ~16us/step
// hidden cost. Now fp16 partials + KSPLIT=32 -> 16.8MB (2.1MB/XCD, L2/L3-
// resident). KCH=768 crosses window-slot scale domains -> exact pow2 acc
// rescale at the boundary. fp16 single-product numerics (R4/R5 proven).

typedef _Float16 f16x8 __attribute__((ext_vector_type(8)));
typedef float    f32x4 __attribute__((ext_vector_type(4)));

#define B_ 128
#define N_ 2048
#define P_ 12
#define K_ (P_*N_)          // 24576
#define KSPLIT 32
#define KCH (K_/KSPLIT)     // 768
#define NPHASE (KCH/64)     // 12 phases of BK=64
#define NTILES 16           // BN=128
#define NKP (K_/64)         // 384 BK64-steps total

#define WPK_BYTES   ((size_t)NTILES*NKP*16384) // 100,663,296 (fp16, tiled)
#define H_SLOT_BYTES ((size_t)B_*N_*2)         // 524,288 per window slot (fp16)
#define H_BYTES     (23*H_SLOT_BYTES)          // 12,058,624
#define PART_BYTES  ((size_t)KSPLIT*B_*N_*2)   // 16,777,216 (fp16!)
#define WS_NEEDED   (WPK_BYTES + H_BYTES + PART_BYTES)   // ~130 MB

// Scale exponents for y_{t+1} (t=0..10): e = round(7.29 + 5.50*t) from the
// variance recursion sigma(y_1)=sqrt(24576), growth sqrt(2048) per step.
__device__ __constant__ int E_TAB[11] = {7, 13, 18, 24, 29, 35, 40, 46, 51, 57, 62};

__device__ __forceinline__ int e_of_slot(int g) {   // g = global slot index 0..22
    return (g < 12) ? 0 : E_TAB[g - 12];
}
__device__ __forceinline__ float pow2f(int e) {      // exact 2^e, |e| < 127
    return __uint_as_float((uint32_t)(127 + e) << 23);
}

union F16x8 { _Float16 h[8]; uint4 q; };
union F16x4v { _Float16 h[4]; uint2 q; };

// ---- H (window) layout: [slot][kblk=k/32][ko=(k%32)/8][b][8 elems] fp16 ----
// A-fragments read per-lane from global: lanes 0..15 (consecutive b) hit a
// contiguous 256B run; 4 ko-groups at stride 2048 -> 4x256B per instruction.
__device__ __forceinline__ uint32_t h_off(int slot, int b, int k) {
    return (uint32_t)slot * (uint32_t)H_SLOT_BYTES
         + (uint32_t)(k >> 5) * 8192u + (uint32_t)(((k >> 3) & 3) << 11)
         + (uint32_t)(b << 4) + (uint32_t)((k & 7) << 1);
}

// ---- Wp (B) layout: tile(nt, pk) = 16 KB covering BK=64 x BN=128 ----
// byte(ksub,c,ko) = ksub*8192 + ((c*64 + ko*16) ^ ((c&7)<<4)); staged linearly
// into LDS; fragment ds_read_b128 uses the R1-R5-proven swizzled pattern.
__device__ __forceinline__ size_t w_tile_base(int nt, int pk) {
    return ((size_t)nt * NKP + (size_t)pk) * 16384;
}

// ---------------- prep: W [12][2048(j)][2048(k)] fp32 -> tiled fp16 ----------------
__global__ void prep_w(const float* __restrict__ W, char* __restrict__ Wp) {
    __shared__ float tile[128][68];   // +4 pad, 34.8 KB
    int id = blockIdx.x;              // 6144 = 16 nt x 384 pk
    int nt = id / NKP, pk = id % NKP;
    int i = pk >> 5;                  // W slice 0..11
    int k0 = (pk & 31) << 6;          // k-in-slice 0..1984
    int j0 = nt << 7;
    int t = threadIdx.x;
    #pragma unroll
    for (int pass = 0; pass < 8; ++pass) {          // coalesced fp32 reads along k
        int jl = pass * 16 + (t >> 4);
        int kq = (t & 15) * 4;
        float4 v = *(const float4*)(W + ((size_t)i * N_ + (j0 + jl)) * N_ + k0 + kq);
        tile[jl][kq + 0] = v.x; tile[jl][kq + 1] = v.y;
        tile[jl][kq + 2] = v.z; tile[jl][kq + 3] = v.w;
    }
    __syncthreads();
    int ksub = t >> 7, c = t & 127;
    char* base = Wp + w_tile_base(nt, pk) + (ksub << 13);
    #pragma unroll
    for (int ko = 0; ko < 4; ++ko) {
        F16x8 o;
        #pragma unroll
        for (int q = 0; q < 8; ++q) o.h[q] = (_Float16)tile[c][ksub * 32 + ko * 8 + q];
        uint32_t off = (uint32_t)((c << 6) + (ko << 4)) ^ (uint32_t)((c & 7) << 4);
        *(uint4*)(base + off) = o.q;
    }
}

// ---------------- prep: x [128][2048][1][12] fp32 -> window slots 0..11 (fp16) ----------------
__global__ void prep_x(const float* __restrict__ x, char* __restrict__ H) {
    int tid = blockIdx.x * 256 + threadIdx.x;   // 32768 threads: (b, n-octet)
    int b = tid >> 8;
    int n0 = (tid & 255) << 3;
    const float4* s4 = (const float4*)(x + ((size_t)b * N_ + n0) * P_);  // 96 consecutive floats
    float4 tmp[24];
    #pragma unroll
    for (int i2 = 0; i2 < 24; ++i2) tmp[i2] = s4[i2];
    #pragma unroll
    for (int p = 0; p < 12; ++p) {
        F16x8 o;
        #pragma unroll
        for (int q = 0; q < 8; ++q) {
            int fi = q * 12 + p;                 // compile-time constant
            float4 blk = tmp[fi >> 2];
            float f = ((fi & 3) == 0) ? blk.x : ((fi & 3) == 1) ? blk.y : ((fi & 3) == 2) ? blk.z : blk.w;
            o.h[q] = (_Float16)f;
        }
        *(uint4*)(H + h_off(p, b, n0)) = o.q;    // n0 % 8 == 0 -> full 16B chunk
    }
}

// ---------------- per-step GEMM: partial[ks][b][j] (fp16, chunk-scale domain) ----------------
// grid 512 = 16 ntiles x 32 ks (bid%8 == ks%8 -> A-chunk sharers on one XCD;
// A-chunk 196 KB L2-hot). B staged once per block via LDS (100 MB/step L3).
// 4 waves as 2x2; wave tile 64x64; block tile 128x128; 2 blocks/CU.
__global__ __launch_bounds__(256, 2) void gemm_step(
        const char* __restrict__ Wp, const char* __restrict__ H,
        _Float16* __restrict__ partial, int st)
{
    __shared__ alignas(16) char ldsB[2][16384];     // [buf][BK=64 x BN=128 fp16 tile]
    const int tid  = threadIdx.x;
    const int lane = tid & 63;
    const int wv   = tid >> 6;                      // 0..3
    const int wr   = wv >> 1;                       // M half
    const int wc   = wv & 1;                        // N half
    const int bid  = blockIdx.x;
    const int ks    = bid % KSPLIT;
    const int ntile = bid / KSPLIT;                 // 0..15
    const int jbase = (ntile << 7) + (wc << 6) + (lane & 15);   // + nf*16
    const int ko   = lane >> 4;                     // k-octet 0..3
    const int kbase = ks * KCH;
    const int pk0  = kbase >> 6;                    // first BK64-step of this chunk

    // B-fragment byte offsets inside one 8KB ksub-half (proven swizzle pattern)
    uint32_t boff[4];
    #pragma unroll
    for (int nf = 0; nf < 4; ++nf) {
        int c = (wc << 6) + (nf << 4) + (lane & 15);
        boff[nf] = (uint32_t)((c << 6) + (ko << 4)) ^ (uint32_t)((c & 7) << 4);
    }

    auto stage = [&](int buf, int ph) {             // 16 KB linear global->LDS
        const char* src = Wp + w_tile_base(ntile, pk0 + ph);
        #pragma unroll
        for (int j = 0; j < 4; ++j) {
            uint32_t o = (uint32_t)(j << 12) + (uint32_t)(tid << 4);
            __builtin_amdgcn_global_load_lds(
                (const __attribute__((address_space(1))) void*)(src + o),
                (__attribute__((address_space(3))) void*)&ldsB[buf][(j << 12) + (wv << 10)], 16, 0, 0);
        }
    };
    auto loadA = [&](int ph, f16x8 a[2][4]) {       // per-lane from L2, coalesced
        #pragma unroll
        for (int ksub = 0; ksub < 2; ++ksub) {
            int kg = kbase + (ph << 6) + (ksub << 5);
            const char* sb = H + (size_t)(st + (kg >> 11)) * H_SLOT_BYTES
                           + (uint32_t)(((kg & 2047) >> 5) << 13) + (uint32_t)(ko << 11);
            #pragma unroll
            for (int m = 0; m < 4; ++m) {
                int brow = (wr << 6) + (m << 4) + (lane & 15);
                a[ksub][m] = *(const f16x8*)(sb + (brow << 4));
            }
        }
    };

    f32x4 acc[4][4];
    #pragma unroll
    for (int m = 0; m < 4; ++m)
        #pragma unroll
        for (int n = 0; n < 4; ++n) acc[m][n] = (f32x4){0.f, 0.f, 0.f, 0.f};

    f16x8 a[2][4];
    loadA(0, a);
    stage(0, 0);
    __syncthreads();                                // drains stage (and loadA)

    int cur_e = e_of_slot(st + (kbase >> 11));
    for (int ph = 0; ph < NPHASE; ++ph) {
        // exact pow2 domain change at window-slot boundary (wave-uniform)
        int e_new = e_of_slot(st + ((kbase + (ph << 6)) >> 11));
        if (e_new != cur_e) {
            float f = pow2f(cur_e - e_new);
            #pragma unroll
            for (int m = 0; m < 4; ++m)
                #pragma unroll
                for (int n = 0; n < 4; ++n) acc[m][n] *= f;
            cur_e = e_new;
        }
        if (ph + 1 < NPHASE) stage((ph & 1) ^ 1, ph + 1);
        const char* lb = &ldsB[ph & 1][0];
        f16x8 bf[2][4];
        #pragma unroll
        for (int ksub = 0; ksub < 2; ++ksub)
            #pragma unroll
            for (int nf = 0; nf < 4; ++nf)
                bf[ksub][nf] = *(const f16x8*)(lb + (ksub << 13) + boff[nf]);
        f16x8 an[2][4];
        if (ph + 1 < NPHASE) loadA(ph + 1, an);     // issued before MFMA; L2 latency hides
        #pragma unroll
        for (int ksub = 0; ksub < 2; ++ksub)
            #pragma unroll
            for (int m = 0; m < 4; ++m)
                #pragma unroll
                for (int nf = 0; nf < 4; ++nf)
                    acc[m][nf] = __builtin_amdgcn_mfma_f32_16x16x32_f16(a[ksub][m], bf[ksub][nf], acc[m][nf], 0, 0, 0);
        #pragma unroll
        for (int ksub = 0; ksub < 2; ++ksub)
            #pragma unroll
            for (int m = 0; m < 4; ++m) a[ksub][m] = an[ksub][m];
        __syncthreads();
    }

    // C/D layout (verified R0-R5): col = lane&15, row = (lane>>4)*4 + reg
    const int r0 = (lane >> 4) << 2;
    _Float16* pb = partial + ((size_t)ks * B_ + (wr << 6) + r0) * N_ + jbase;
    #pragma unroll
    for (int m = 0; m < 4; ++m)
        #pragma unroll
        for (int n = 0; n < 4; ++n)
            #pragma unroll
            for (int r = 0; r < 4; ++r)
                pb[(size_t)(m * 16 + r) * N_ + n * 16] = (_Float16)acc[m][n][r];
}

// ---------------- reduce 32 fp16 partials -> y; emit output + next window slot ----------------
__global__ void reduce_step(const _Float16* __restrict__ partial, float* __restrict__ out,
                            char* __restrict__ H, int t)
{
    int tid = blockIdx.x * 256 + threadIdx.x;   // 65536 threads: (b, n-quad)
    int b = tid >> 9;
    int n0 = (tid & 511) << 2;
    float s0 = 0.f, s1 = 0.f, s2 = 0.f, s3 = 0.f;
    #pragma unroll 4
    for (int c = 0; c < KSPLIT; ++c) {          // chunk scale = e of its LAST slot
        float sc = pow2f(e_of_slot(t + ((c * KCH + (KCH - 64)) >> 11)));
        F16x4v p;
        p.q = *(const uint2*)(partial + ((size_t)c * B_ + b) * N_ + n0);
        s0 += (float)p.h[0] * sc; s1 += (float)p.h[1] * sc;
        s2 += (float)p.h[2] * sc; s3 += (float)p.h[3] * sc;
    }
    float* ob = out + ((size_t)b * N_ + n0) * P_ + t;
    ob[0 * P_] = s0; ob[1 * P_] = s1; ob[2 * P_] = s2; ob[3 * P_] = s3;
    if (t < 11) {                                // y_12 never re-enters the window
        float ds = pow2f(-E_TAB[t]);             // store next slot scaled by 2^-e
        F16x4v o;
        o.h[0] = (_Float16)(s0 * ds); o.h[1] = (_Float16)(s1 * ds);
        o.h[2] = (_Float16)(s2 * ds); o.h[3] = (_Float16)(s3 * ds);
        *(uint2*)(H + h_off(12 + t, b, n0)) = o.q;   // 8B contiguous in this layout
    }
}

// ---------------- insurance: naive fp32 path if workspace is too small ----------------
__global__ void naive_step(const float* __restrict__ x, const float* __restrict__ W,
                           float* __restrict__ out, int t)
{
    int tid = blockIdx.x * 256 + threadIdx.x;   // 262144 threads: (b, j)
    int b = tid >> 11;
    int j = tid & (N_ - 1);
    float acc = 0.f;
    for (int i = 0; i < 12; ++i) {
        int g = t + i;
        const float* src = (g < 12) ? (x   + (size_t)b * (N_ * 12) + g)
                                    : (out + (size_t)b * (N_ * 12) + (g - 12));
        const float* wr = W + ((size_t)i * N_ + j) * N_;
        for (int k = 0; k < N_; ++k)
            acc += wr[k] * src[(size_t)k * 12];
    }
    out[((size_t)b * N_ + j) * 12 + t] = acc;
}

extern "C" void kernel_launch(void* const* d_in, const int* in_sizes, int n_in,
                              void* d_out, int out_size, void* d_ws, size_t ws_size,
                              hipStream_t stream)
{
    const float* x = (const float*)d_in[0];
    const float* W = (const float*)d_in[1];
    float* out = (float*)d_out;

    if (ws_size < WS_NEEDED) {                  // fallback: correct but slow
        for (int t = 0; t < 12; ++t)
            naive_step<<<1024, 256, 0, stream>>>(x, W, out, t);
        return;
    }

    char* ws = (char*)d_ws;
    char* Wp = ws;
    char* H  = Wp + WPK_BYTES;
    _Float16* partial = (_Float16*)(H + H_BYTES);

    prep_w<<<6144, 256, 0, stream>>>(W, Wp);
    prep_x<<<128, 256, 0, stream>>>(x, H);
    for (int t = 0; t < 12; ++t) {
        gemm_step<<<512, 256, 0, stream>>>(Wp, H, partial, t);
        reduce_step<<<256, 256, 0, stream>>>(partial, out, H, t);
    }
}